// Round 1
// baseline (84.780 us; speedup 1.0000x reference)
//
#include <hip/hip_runtime.h>

// Problem constants (from reference):
//   L=36, G=180, A=0.2, RO=2.5, RMAX=13, B=27, CELLS=27^3=19683
//   NRAD=8, NL=4 -> 16 masked (l,m) pairs, VCELL=0.008
#define G 180
#define NRAD 8
#define RO_F 2.5f
#define A_F 0.2f
#define VCELL_F 0.008f
#define CELLS 19683
#define SLABS 8
#define NATOMS 64

// lm ordering (matches coeff[:, MASK].reshape(-1)):
// 0:(0,0) 1:(1,-1) 2:(1,0) 3:(1,1) 4:(2,-2) 5:(2,-1) 6:(2,0) 7:(2,1) 8:(2,2)
// 9:(3,-3) 10:(3,-2) 11:(3,-1) 12:(3,0) 13:(3,1) 14:(3,2) 15:(3,3)

__global__ __launch_bounds__(256, 2) void proj_kernel(
    const float* __restrict__ rho, const float* __restrict__ pos,
    float* __restrict__ ws)
{
    const int atom = blockIdx.y;
    const int slab = blockIdx.x;
    const int tid  = threadIdx.x;
    const int lane = tid & 63;
    const int waveid = tid >> 6;

    const float px = pos[atom*3+0], py = pos[atom*3+1], pz = pos[atom*3+2];
    // cm = round(pos/A); dr = pos - A*cm   (A = 0.2 -> pos*5)
    const float cmx = rintf(px * 5.0f), cmy = rintf(py * 5.0f), cmz = rintf(pz * 5.0f);
    const float drx = px - A_F*cmx, dry = py - A_F*cmy, drz = pz - A_F*cmz;
    const int icx = (int)cmx - 13, icy = (int)cmy - 13, icz = (int)cmz - 13;

    float acc[128];
    #pragma unroll
    for (int j = 0; j < 128; ++j) acc[j] = 0.0f;

    for (int c = slab*256 + tid; c < CELLS; c += SLABS*256) {
        int i = c / 729;
        int rem = c - i*729;
        int j = rem / 27;
        int k = rem - j*27;
        // periodic wrap: i+icx in [-13, 193]
        int gx = i + icx; gx += (gx < 0) ? G : 0; gx -= (gx >= G) ? G : 0;
        int gy = j + icy; gy += (gy < 0) ? G : 0; gy -= (gy >= G) ? G : 0;
        int gz = k + icz; gz += (gz < 0) ? G : 0; gz -= (gz >= G) ? G : 0;
        float s = rho[(gx*G + gy)*G + gz];

        float x = (float)(i-13)*A_F - drx;
        float y = (float)(j-13)*A_F - dry;
        float z = (float)(k-13)*A_F - drz;
        float r2 = x*x + y*y + z*z;
        float inv = rsqrtf(fmaxf(r2, 1e-24f));
        float R = r2 * inv;                 // == sqrt(r2)
        if (R < RO_F) {
            float t = RO_F - R;
            float ux = x*inv, uy = y*inv, uz = z*inv;
            float uz2 = uz*uz;
            float ux2 = ux*ux, uy2 = uy*uy;
            float ys[16];
            ys[0]  = 0.28209479177f * s;
            ys[1]  = 0.48860251190f * uy * s;
            ys[2]  = 0.48860251190f * uz * s;
            ys[3]  = 0.48860251190f * ux * s;
            ys[4]  = 1.09254843059f * ux*uy * s;            // 2 * 0.54627 * ux uy
            ys[5]  = 1.09254843059f * uy*uz * s;
            ys[6]  = 0.31539156525f * (3.0f*uz2 - 1.0f) * s;
            ys[7]  = 1.09254843059f * ux*uz * s;
            ys[8]  = 0.54627421530f * (ux2 - uy2) * s;
            ys[9]  = 0.59004358993f * uy*(3.0f*ux2 - uy2) * s;
            ys[10] = 2.89061144264f * ux*uy*uz * s;         // 2 * 1.44530572
            ys[11] = 0.45704579946f * uy*(5.0f*uz2 - 1.0f) * s;
            ys[12] = 0.37317633259f * uz*(5.0f*uz2 - 3.0f) * s;
            ys[13] = 0.45704579946f * ux*(5.0f*uz2 - 1.0f) * s;
            ys[14] = 1.44530572132f * (ux2 - uy2)*uz * s;
            ys[15] = 0.59004358993f * ux*(ux2 - 3.0f*uy2) * s;

            float p = r2 * t * t;           // phi_0 = R^2 (RO-R)^2
            #pragma unroll
            for (int n = 0; n < NRAD; ++n) {
                #pragma unroll
                for (int q = 0; q < 16; ++q)
                    acc[n*16+q] = fmaf(p, ys[q], acc[n*16+q]);
                p *= t;                     // phi_{n+1} = phi_n * (RO-R)
            }
        }
    }

    // Block reduction: per-wave LDS transpose (pad 33 -> conflict-free b32),
    // then one coalesced atomicAdd per 32-value chunk.
    __shared__ float red[4][64][33];
    const int col  = lane & 31;
    const int half = lane >> 5;
    #pragma unroll
    for (int cb = 0; cb < 4; ++cb) {
        __syncthreads();
        #pragma unroll
        for (int q = 0; q < 32; ++q)
            red[waveid][lane][q] = acc[cb*32 + q];
        __syncthreads();
        float csum = 0.0f;
        #pragma unroll
        for (int r = 0; r < 32; ++r)
            csum += red[waveid][half*32 + r][col];
        atomicAdd(&ws[atom*128 + cb*32 + col], csum);
    }
}

// coeff[n][lm] = VCELL * sum_k W[n][k] * acc[k][lm]
__global__ void finalize_kernel(const float* __restrict__ ws,
                                const float* __restrict__ W,
                                float* __restrict__ out)
{
    const int atom = blockIdx.x;
    const int t = threadIdx.x;        // 128 threads
    const int n = t >> 4, q = t & 15;
    float sum = 0.0f;
    #pragma unroll
    for (int k = 0; k < 8; ++k)
        sum = fmaf(W[n*8+k], ws[atom*128 + k*16 + q], sum);
    out[atom*128 + t] = sum * VCELL_F;
}

extern "C" void kernel_launch(void* const* d_in, const int* in_sizes, int n_in,
                              void* d_out, int out_size, void* d_ws, size_t ws_size,
                              hipStream_t stream) {
    const float* rho = (const float*)d_in[0];   // 180^3
    const float* pos = (const float*)d_in[1];   // 64 x 3
    const float* W   = (const float*)d_in[2];   // 8 x 8
    float* out = (float*)d_out;                 // 64 x 128 fp32
    float* ws  = (float*)d_ws;                  // 64*128 fp32 accumulators

    hipMemsetAsync(ws, 0, NATOMS*128*sizeof(float), stream);
    dim3 grid(SLABS, NATOMS);
    proj_kernel<<<grid, 256, 0, stream>>>(rho, pos, ws);
    finalize_kernel<<<NATOMS, 128, 0, stream>>>(ws, W, out);
}

// Round 2
// 78.655 us; speedup vs baseline: 1.0779x; 1.0779x over previous
//
#include <hip/hip_runtime.h>

// Problem constants (from reference):
//   L=36, G=180, A=0.2, RO=2.5, RMAX=13, B=27, CELLS=27^3=19683
//   NRAD=8, NL=4 -> 16 masked (l,m) pairs, VCELL=0.008
#define G 180
#define NRAD 8
#define RO_F 2.5f
#define A_F 0.2f
#define VCELL_F 0.008f
#define CELLS 19683
#define SLABS 8
#define NATOMS 64

// lm ordering (matches coeff[:, MASK].reshape(-1)):
// 0:(0,0) 1:(1,-1) 2:(1,0) 3:(1,1) 4:(2,-2) 5:(2,-1) 6:(2,0) 7:(2,1) 8:(2,2)
// 9:(3,-3) 10:(3,-2) 11:(3,-1) 12:(3,0) 13:(3,1) 14:(3,2) 15:(3,3)

// ws layout: ws[atom][slab][128] partial sums (no atomics, no zero-init:
// every slot is fully overwritten each call — safe vs 0xAA poison).
__global__ __launch_bounds__(256, 2) void proj_kernel(
    const float* __restrict__ rho, const float* __restrict__ pos,
    float* __restrict__ ws)
{
    const int atom = blockIdx.y;
    const int slab = blockIdx.x;
    const int tid  = threadIdx.x;
    const int lane = tid & 63;
    const int waveid = tid >> 6;

    const float px = pos[atom*3+0], py = pos[atom*3+1], pz = pos[atom*3+2];
    // cm = round(pos/A); dr = pos - A*cm   (A = 0.2 -> pos*5)
    const float cmx = rintf(px * 5.0f), cmy = rintf(py * 5.0f), cmz = rintf(pz * 5.0f);
    const float drx = px - A_F*cmx, dry = py - A_F*cmy, drz = pz - A_F*cmz;
    const int icx = (int)cmx - 13, icy = (int)cmy - 13, icz = (int)cmz - 13;

    float acc[128];
    #pragma unroll
    for (int j = 0; j < 128; ++j) acc[j] = 0.0f;

    for (int c = slab*256 + tid; c < CELLS; c += SLABS*256) {
        int i = c / 729;
        int rem = c - i*729;
        int j = rem / 27;
        int k = rem - j*27;
        // periodic wrap: i+icx in [-13, 193]
        int gx = i + icx; gx += (gx < 0) ? G : 0; gx -= (gx >= G) ? G : 0;
        int gy = j + icy; gy += (gy < 0) ? G : 0; gy -= (gy >= G) ? G : 0;
        int gz = k + icz; gz += (gz < 0) ? G : 0; gz -= (gz >= G) ? G : 0;
        float s = rho[(gx*G + gy)*G + gz];

        float x = (float)(i-13)*A_F - drx;
        float y = (float)(j-13)*A_F - dry;
        float z = (float)(k-13)*A_F - drz;
        float r2 = x*x + y*y + z*z;
        float inv = rsqrtf(fmaxf(r2, 1e-24f));
        float R = r2 * inv;                 // == sqrt(r2)
        if (R < RO_F) {
            float t = RO_F - R;
            float ux = x*inv, uy = y*inv, uz = z*inv;
            float uz2 = uz*uz;
            float ux2 = ux*ux, uy2 = uy*uy;
            float ys[16];
            ys[0]  = 0.28209479177f * s;
            ys[1]  = 0.48860251190f * uy * s;
            ys[2]  = 0.48860251190f * uz * s;
            ys[3]  = 0.48860251190f * ux * s;
            ys[4]  = 1.09254843059f * ux*uy * s;            // 2 * 0.54627 * ux uy
            ys[5]  = 1.09254843059f * uy*uz * s;
            ys[6]  = 0.31539156525f * (3.0f*uz2 - 1.0f) * s;
            ys[7]  = 1.09254843059f * ux*uz * s;
            ys[8]  = 0.54627421530f * (ux2 - uy2) * s;
            ys[9]  = 0.59004358993f * uy*(3.0f*ux2 - uy2) * s;
            ys[10] = 2.89061144264f * ux*uy*uz * s;         // 2 * 1.44530572
            ys[11] = 0.45704579946f * uy*(5.0f*uz2 - 1.0f) * s;
            ys[12] = 0.37317633259f * uz*(5.0f*uz2 - 3.0f) * s;
            ys[13] = 0.45704579946f * ux*(5.0f*uz2 - 1.0f) * s;
            ys[14] = 1.44530572132f * (ux2 - uy2)*uz * s;
            ys[15] = 0.59004358993f * ux*(ux2 - 3.0f*uy2) * s;

            float p = r2 * t * t;           // phi_0 = R^2 (RO-R)^2
            #pragma unroll
            for (int n = 0; n < NRAD; ++n) {
                #pragma unroll
                for (int q = 0; q < 16; ++q)
                    acc[n*16+q] = fmaf(p, ys[q], acc[n*16+q]);
                p *= t;                     // phi_{n+1} = phi_n * (RO-R)
            }
        }
    }

    // Block reduction, no atomics:
    //  stage 1: per-wave LDS transpose (pad 33 -> conflict-free), each lane
    //           sums a 32-row half-column -> partial per (wave, half, col)
    //  stage 2: 8 partials per output idx gathered by tid<128
    __shared__ float red[4][64][33];      // 33 KB
    __shared__ float stage[4][8][32];     // 4 KB
    const int col  = lane & 31;
    const int half = lane >> 5;
    #pragma unroll
    for (int cb = 0; cb < 4; ++cb) {
        __syncthreads();                  // WAR: previous chunk's reads done
        #pragma unroll
        for (int q = 0; q < 32; ++q)
            red[waveid][lane][q] = acc[cb*32 + q];
        __syncthreads();
        float csum = 0.0f;
        #pragma unroll
        for (int r = 0; r < 32; ++r)
            csum += red[waveid][half*32 + r][col];
        stage[cb][waveid*2 + half][col] = csum;
    }
    __syncthreads();
    if (tid < 128) {
        const int cb = tid >> 5, c2 = tid & 31;
        float sum = 0.0f;
        #pragma unroll
        for (int r = 0; r < 8; ++r)
            sum += stage[cb][r][c2];
        ws[(atom*SLABS + slab)*128 + tid] = sum;
    }
}

// out[atom][n*16+q] = VCELL * sum_k W[n][k] * (sum_slab ws[atom][slab][k*16+q])
__global__ void finalize_kernel(const float* __restrict__ ws,
                                const float* __restrict__ W,
                                float* __restrict__ out)
{
    const int atom = blockIdx.x;
    const int t = threadIdx.x;        // 128 threads
    const int n = t >> 4, q = t & 15;
    const float* base = ws + atom*SLABS*128;
    float red[8];
    #pragma unroll
    for (int k = 0; k < 8; ++k) {
        float sk = 0.0f;
        #pragma unroll
        for (int s = 0; s < 8; ++s)
            sk += base[s*128 + k*16 + q];
        red[k] = sk;
    }
    float sum = 0.0f;
    #pragma unroll
    for (int k = 0; k < 8; ++k)
        sum = fmaf(W[n*8+k], red[k], sum);
    out[atom*128 + t] = sum * VCELL_F;
}

extern "C" void kernel_launch(void* const* d_in, const int* in_sizes, int n_in,
                              void* d_out, int out_size, void* d_ws, size_t ws_size,
                              hipStream_t stream) {
    const float* rho = (const float*)d_in[0];   // 180^3
    const float* pos = (const float*)d_in[1];   // 64 x 3
    const float* W   = (const float*)d_in[2];   // 8 x 8
    float* out = (float*)d_out;                 // 64 x 128 fp32
    float* ws  = (float*)d_ws;                  // 64*8*128 fp32 partials

    dim3 grid(SLABS, NATOMS);
    proj_kernel<<<grid, 256, 0, stream>>>(rho, pos, ws);
    finalize_kernel<<<NATOMS, 128, 0, stream>>>(ws, W, out);
}